// Round 1
// baseline (375.413 us; speedup 1.0000x reference)
//
#include <hip/hip_runtime.h>
#include <hip/hip_bf16.h>

// Problem constants
#define T_DIM 2048
#define B_DIM 8
#define D_DIM 1024
#define M_DIM (T_DIM * B_DIM)     // 16384
#define N_DIM D_DIM               // 1024
#define K_DIM D_DIM               // 1024
#define NCH (B_DIM * D_DIM)       // 8192 channels
#define NCH4 (NCH / 4)            // 2048 float4 channels
#define CHUNKS 64
#define CHUNK_LEN 32              // 64*32 = 2048 = T

typedef __attribute__((ext_vector_type(8))) short bf16x8;
typedef __attribute__((ext_vector_type(4))) float f32x4;

__device__ __forceinline__ unsigned short bf16_rne(float f) {
    unsigned u = __float_as_uint(f);
    unsigned r = u + 0x7fffu + ((u >> 16) & 1u);
    return (unsigned short)(r >> 16);
}

__device__ __forceinline__ float sigmoidf(float z) {
    return 1.0f / (1.0f + __expf(-z));
}

__device__ __forceinline__ void load_lds16(const void* g, void* l) {
    __builtin_amdgcn_global_load_lds(
        (const __attribute__((address_space(1))) void*)g,
        (__attribute__((address_space(3))) void*)l,
        16, 0, 0);
}

// ---------------- fp32 -> bf16 convert ----------------
__global__ void f32_to_bf16_kernel(const float4* __restrict__ in,
                                   ushort4* __restrict__ out, int n4) {
    int i = blockIdx.x * blockDim.x + threadIdx.x;
    if (i < n4) {
        float4 f = in[i];
        ushort4 o;
        o.x = bf16_rne(f.x);
        o.y = bf16_rne(f.y);
        o.z = bf16_rne(f.z);
        o.w = bf16_rne(f.w);
        out[i] = o;
    }
}

// ---------------- bf16 MFMA GEMM: C = act(A @ W^T + bias) ----------------
// A: [M,K] bf16 row-major.  W: [N,K] bf16 row-major (B^T layout — k contiguous
// for both operands, so both fragments are contiguous 16B LDS reads).
// 128x128 block tile, BK=64, 256 threads = 4 waves in 2x2, each wave 64x64
// via 4x4 grid of 16x16x32 MFMAs.
__global__ __launch_bounds__(256) void gemm_bias_act_kernel(
    const unsigned short* __restrict__ A,
    const unsigned short* __restrict__ W,
    const float* __restrict__ bias,
    float* __restrict__ C,
    int apply_sigmoid) {
    __shared__ __attribute__((aligned(16))) unsigned short As[128 * 64];
    __shared__ __attribute__((aligned(16))) unsigned short Bs[128 * 64];

    const int tid = threadIdx.x;
    const int lane = tid & 63;
    const int w = tid >> 6;          // wave 0..3
    const int wm = w >> 1;           // wave row (0..1)
    const int wn = w & 1;            // wave col (0..1)
    const int quad = lane >> 4;      // 0..3
    const int l16 = lane & 15;

    const int bm = blockIdx.y * 128;
    const int bn = blockIdx.x * 128;

    // staging: each lane moves 16B; wave-issue = 8 rows x 64 cols, LDS dest
    // contiguous = wave-uniform base + lane*16 (global_load_lds constraint)
    const int st_row = lane >> 3;          // 0..7 row within issue
    const int st_col = (lane & 7) * 8;     // element col

    f32x4 zero = {0.f, 0.f, 0.f, 0.f};
    f32x4 acc[4][4];
#pragma unroll
    for (int i = 0; i < 4; ++i)
#pragma unroll
        for (int j = 0; j < 4; ++j) acc[i][j] = zero;

    for (int kt = 0; kt < K_DIM / 64; ++kt) {
        const int k0 = kt * 64;
#pragma unroll
        for (int j = 0; j < 4; ++j) {
            const int r = w * 32 + j * 8;  // wave-uniform base row
            load_lds16(A + (size_t)(bm + r + st_row) * K_DIM + k0 + st_col,
                       &As[r * 64]);
            load_lds16(W + (size_t)(bn + r + st_row) * K_DIM + k0 + st_col,
                       &Bs[r * 64]);
        }
        __syncthreads();
#pragma unroll
        for (int s = 0; s < 2; ++s) {
            bf16x8 af[4], bfr[4];
#pragma unroll
            for (int i = 0; i < 4; ++i)
                af[i] = *(const bf16x8*)&As[(wm * 64 + i * 16 + l16) * 64 + s * 32 + quad * 8];
#pragma unroll
            for (int i = 0; i < 4; ++i)
                bfr[i] = *(const bf16x8*)&Bs[(wn * 64 + i * 16 + l16) * 64 + s * 32 + quad * 8];
#pragma unroll
            for (int i = 0; i < 4; ++i)
#pragma unroll
                for (int j = 0; j < 4; ++j)
                    acc[i][j] = __builtin_amdgcn_mfma_f32_16x16x32_bf16(
                        af[i], bfr[j], acc[i][j], 0, 0, 0);
        }
        __syncthreads();
    }

    // epilogue: C/D layout col = lane&15, row = quad*4 + reg
#pragma unroll
    for (int j = 0; j < 4; ++j) {
        const int n = bn + wn * 64 + j * 16 + l16;
        const float bias_n = bias[n];
#pragma unroll
        for (int i = 0; i < 4; ++i) {
            const int m0 = bm + wm * 64 + i * 16 + quad * 4;
#pragma unroll
            for (int r = 0; r < 4; ++r) {
                float val = acc[i][j][r] + bias_n;
                if (apply_sigmoid) val = sigmoidf(val);
                C[(size_t)(m0 + r) * N_DIM + n] = val;
            }
        }
    }
}

// ---------------- chunked parallel scan ----------------
// h_t = a_t*h_{t-1} + (1-a_t)*v_t  == affine h_out = P*h_in + Q per chunk.

// Phase 1: per (chunk, channel4) compute chunk composition (P,Q).
__global__ __launch_bounds__(256) void scan_phase1_kernel(
    const float4* __restrict__ alpha,  // [T][NCH4]
    const float4* __restrict__ v,      // [T][NCH4]
    float4* __restrict__ P,            // [CHUNKS][NCH4]
    float4* __restrict__ Q) {
    const int j4 = blockIdx.x * 256 + threadIdx.x;  // 0..NCH4-1
    const int c = blockIdx.y;
    float4 Pr = {1.f, 1.f, 1.f, 1.f};
    float4 Qr = {0.f, 0.f, 0.f, 0.f};
    size_t base = (size_t)c * CHUNK_LEN * NCH4 + j4;
#pragma unroll 4
    for (int t = 0; t < CHUNK_LEN; ++t) {
        float4 a = alpha[base + (size_t)t * NCH4];
        float4 vv = v[base + (size_t)t * NCH4];
        Pr.x *= a.x; Pr.y *= a.y; Pr.z *= a.z; Pr.w *= a.w;
        Qr.x = a.x * Qr.x + (1.f - a.x) * vv.x;
        Qr.y = a.y * Qr.y + (1.f - a.y) * vv.y;
        Qr.z = a.z * Qr.z + (1.f - a.z) * vv.z;
        Qr.w = a.w * Qr.w + (1.f - a.w) * vv.w;
    }
    P[(size_t)c * NCH4 + j4] = Pr;
    Q[(size_t)c * NCH4 + j4] = Qr;
}

// Phase 2: exclusive prefix over chunks (2048 threads, 64 sequential steps).
__global__ __launch_bounds__(256) void scan_phase2_kernel(
    const float4* __restrict__ P, const float4* __restrict__ Q,
    const float4* __restrict__ h0,  // [NCH4]
    float4* __restrict__ Hc) {      // [CHUNKS][NCH4] = h at chunk start
    const int j4 = blockIdx.x * 256 + threadIdx.x;
    float4 h = h0[j4];
#pragma unroll 8
    for (int c = 0; c < CHUNKS; ++c) {
        Hc[(size_t)c * NCH4 + j4] = h;
        float4 p = P[(size_t)c * NCH4 + j4];
        float4 q = Q[(size_t)c * NCH4 + j4];
        h.x = p.x * h.x + q.x;
        h.y = p.y * h.y + q.y;
        h.z = p.z * h.z + q.z;
        h.w = p.w * h.w + q.w;
    }
}

// Phase 3: replay chunk with correct incoming h; in-place overwrite:
// alpha region -> output, v region -> h[t+1].
__global__ __launch_bounds__(256) void scan_phase3_kernel(
    float4* __restrict__ alpha_out,  // in: alpha[t], out: output[t]
    float4* __restrict__ v_h,        // in: v[t] (at h[t+1] slot), out: h[t+1]
    const float4* __restrict__ Hc) {
    const int j4 = blockIdx.x * 256 + threadIdx.x;
    const int c = blockIdx.y;
    float4 h = Hc[(size_t)c * NCH4 + j4];
    size_t base = (size_t)c * CHUNK_LEN * NCH4 + j4;
#pragma unroll 4
    for (int t = 0; t < CHUNK_LEN; ++t) {
        float4 a = alpha_out[base + (size_t)t * NCH4];
        float4 vv = v_h[base + (size_t)t * NCH4];
        h.x = a.x * h.x + (1.f - a.x) * vv.x;
        h.y = a.y * h.y + (1.f - a.y) * vv.y;
        h.z = a.z * h.z + (1.f - a.z) * vv.z;
        h.w = a.w * h.w + (1.f - a.w) * vv.w;
        float4 o;
        o.x = h.x * h.x * sigmoidf(h.x);
        o.y = h.y * h.y * sigmoidf(h.y);
        o.z = h.z * h.z * sigmoidf(h.z);
        o.w = h.w * h.w * sigmoidf(h.w);
        alpha_out[base + (size_t)t * NCH4] = o;
        v_h[base + (size_t)t * NCH4] = h;
    }
}

extern "C" void kernel_launch(void* const* d_in, const int* in_sizes, int n_in,
                              void* d_out, int out_size, void* d_ws, size_t ws_size,
                              hipStream_t stream) {
    const float* x  = (const float*)d_in[0];   // [T,B,D]
    const float* h0 = (const float*)d_in[1];   // [B,D]
    const float* Wa = (const float*)d_in[2];   // [D,D]
    const float* ba = (const float*)d_in[3];   // [D]
    const float* Wv = (const float*)d_in[4];   // [D,D]
    const float* bv = (const float*)d_in[5];   // [D]

    float* out = (float*)d_out;                       // output region [T][NCH]
    float* hbase = out + (size_t)T_DIM * NCH;         // h region [T+1][NCH]
    float* alpha = out;                               // temp alpha in output region
    float* vbuf = hbase + NCH;                        // temp v in h[1..T]

    char* ws = (char*)d_ws;
    unsigned short* xb  = (unsigned short*)ws;                       // 32 MB
    unsigned short* Wab = (unsigned short*)(ws + 33554432);          // 2 MB
    unsigned short* Wvb = (unsigned short*)(ws + 35651584);          // 2 MB
    float* P  = (float*)(ws + 37748736);                             // 2 MB
    float* Q  = (float*)(ws + 39845888);                             // 2 MB
    float* Hc = (float*)(ws + 41943040);                             // 2 MB

    // 1. convert inputs to bf16
    f32_to_bf16_kernel<<<(M_DIM * K_DIM / 4) / 256, 256, 0, stream>>>(
        (const float4*)x, (ushort4*)xb, M_DIM * K_DIM / 4);
    f32_to_bf16_kernel<<<(N_DIM * K_DIM / 4) / 256, 256, 0, stream>>>(
        (const float4*)Wa, (ushort4*)Wab, N_DIM * K_DIM / 4);
    f32_to_bf16_kernel<<<(N_DIM * K_DIM / 4) / 256, 256, 0, stream>>>(
        (const float4*)Wv, (ushort4*)Wvb, N_DIM * K_DIM / 4);

    // 2. GEMMs: alpha = sigmoid(x Wa^T + ba)  -> output region
    //           v     =         x Wv^T + bv   -> h[1..T] region
    dim3 ggrid(N_DIM / 128, M_DIM / 128);
    gemm_bias_act_kernel<<<ggrid, 256, 0, stream>>>(xb, Wab, ba, alpha, 1);
    gemm_bias_act_kernel<<<ggrid, 256, 0, stream>>>(xb, Wvb, bv, vbuf, 0);

    // 3. h[0] = h0
    hipMemcpyAsync(hbase, h0, (size_t)NCH * sizeof(float),
                   hipMemcpyDeviceToDevice, stream);

    // 4. chunked scan
    dim3 sgrid(NCH4 / 256, CHUNKS);
    scan_phase1_kernel<<<sgrid, 256, 0, stream>>>(
        (const float4*)alpha, (const float4*)vbuf, (float4*)P, (float4*)Q);
    scan_phase2_kernel<<<NCH4 / 256, 256, 0, stream>>>(
        (const float4*)P, (const float4*)Q, (const float4*)h0, (float4*)Hc);
    scan_phase3_kernel<<<sgrid, 256, 0, stream>>>(
        (float4*)alpha, (float4*)vbuf, (const float4*)Hc);
}

// Round 2
// 359.765 us; speedup vs baseline: 1.0435x; 1.0435x over previous
//
#include <hip/hip_runtime.h>
#include <hip/hip_bf16.h>

// Problem constants
#define T_DIM 2048
#define B_DIM 8
#define D_DIM 1024
#define M_DIM (T_DIM * B_DIM)     // 16384
#define K_DIM D_DIM               // 1024
#define NW_DIM (2 * D_DIM)        // 2048 combined GEMM cols (alpha | v)
#define NCH (B_DIM * D_DIM)       // 8192 channels
#define NCH4 (NCH / 4)            // 2048 float4 channels
#define CHUNKS 64
#define CHUNK_LEN 32              // 64*32 = 2048 = T

typedef __attribute__((ext_vector_type(8))) short bf16x8;
typedef __attribute__((ext_vector_type(4))) float f32x4;

__device__ __forceinline__ unsigned short bf16_rne(float f) {
    unsigned u = __float_as_uint(f);
    unsigned r = u + 0x7fffu + ((u >> 16) & 1u);
    return (unsigned short)(r >> 16);
}

__device__ __forceinline__ float sigmoidf(float z) {
    return 1.0f / (1.0f + __expf(-z));
}

__device__ __forceinline__ void load_lds16(const void* g, void* l) {
    __builtin_amdgcn_global_load_lds(
        (const __attribute__((address_space(1))) void*)g,
        (__attribute__((address_space(3))) void*)l,
        16, 0, 0);
}

// ---------------- fp32 -> bf16 convert (x) ----------------
__global__ void f32_to_bf16_kernel(const float4* __restrict__ in,
                                   ushort4* __restrict__ out, int n4) {
    int i = blockIdx.x * blockDim.x + threadIdx.x;
    if (i < n4) {
        float4 f = in[i];
        ushort4 o;
        o.x = bf16_rne(f.x);
        o.y = bf16_rne(f.y);
        o.z = bf16_rne(f.z);
        o.w = bf16_rne(f.w);
        out[i] = o;
    }
}

// ---------------- weights convert: Wcat = [Wa ; Wv] bf16 ----------------
__global__ void conv_weights_kernel(const float4* __restrict__ Wa,
                                    const float4* __restrict__ Wv,
                                    ushort4* __restrict__ Wcat) {
    const int half4 = D_DIM * D_DIM / 4;  // 262144
    int i = blockIdx.x * blockDim.x + threadIdx.x;  // 0 .. 2*half4-1
    float4 f = (i < half4) ? Wa[i] : Wv[i - half4];
    ushort4 o;
    o.x = bf16_rne(f.x);
    o.y = bf16_rne(f.y);
    o.z = bf16_rne(f.z);
    o.w = bf16_rne(f.w);
    Wcat[i] = o;
}

// ---------------- fused bf16 MFMA GEMM ----------------
// A: [M,K] bf16 row-major.  Wcat: [2N?,K] = [2048,1024] bf16 row-major
// (B^T layout). cols [0,1024): alpha = sigmoid(xWa^T + ba) -> alpha_dst
// cols [1024,2048): v = xWv^T + bv -> v_dst. Both dsts have row stride 1024.
// 128x128 block tile, BK=64, 256 threads = 4 waves in 2x2, each wave 64x64
// via 4x4 grid of 16x16x32 MFMAs.
__global__ __launch_bounds__(256) void gemm_fused_kernel(
    const unsigned short* __restrict__ A,
    const unsigned short* __restrict__ W,
    const float* __restrict__ ba,
    const float* __restrict__ bv,
    float* __restrict__ alpha_dst,
    float* __restrict__ v_dst) {
    __shared__ __attribute__((aligned(16))) unsigned short As[128 * 64];
    __shared__ __attribute__((aligned(16))) unsigned short Bs[128 * 64];

    const int tid = threadIdx.x;
    const int lane = tid & 63;
    const int w = tid >> 6;          // wave 0..3
    const int wm = w >> 1;           // wave row (0..1)
    const int wn = w & 1;            // wave col (0..1)
    const int quad = lane >> 4;      // 0..3
    const int l16 = lane & 15;

    const int bm = blockIdx.y * 128;
    const int bn = blockIdx.x * 128;  // 0..1920, col in the 2048-wide space

    const int st_row = lane >> 3;          // 0..7 row within wave-issue
    const int st_col = (lane & 7) * 8;     // element col

    f32x4 zero = {0.f, 0.f, 0.f, 0.f};
    f32x4 acc[4][4];
#pragma unroll
    for (int i = 0; i < 4; ++i)
#pragma unroll
        for (int j = 0; j < 4; ++j) acc[i][j] = zero;

    for (int kt = 0; kt < K_DIM / 64; ++kt) {
        const int k0 = kt * 64;
#pragma unroll
        for (int j = 0; j < 4; ++j) {
            const int r = w * 32 + j * 8;  // wave-uniform base row
            load_lds16(A + (size_t)(bm + r + st_row) * K_DIM + k0 + st_col,
                       &As[r * 64]);
            load_lds16(W + (size_t)(bn + r + st_row) * K_DIM + k0 + st_col,
                       &Bs[r * 64]);
        }
        __syncthreads();
#pragma unroll
        for (int s = 0; s < 2; ++s) {
            bf16x8 af[4], bfr[4];
#pragma unroll
            for (int i = 0; i < 4; ++i)
                af[i] = *(const bf16x8*)&As[(wm * 64 + i * 16 + l16) * 64 + s * 32 + quad * 8];
#pragma unroll
            for (int i = 0; i < 4; ++i)
                bfr[i] = *(const bf16x8*)&Bs[(wn * 64 + i * 16 + l16) * 64 + s * 32 + quad * 8];
#pragma unroll
            for (int i = 0; i < 4; ++i)
#pragma unroll
                for (int j = 0; j < 4; ++j)
                    acc[i][j] = __builtin_amdgcn_mfma_f32_16x16x32_bf16(
                        af[i], bfr[j], acc[i][j], 0, 0, 0);
        }
        __syncthreads();
    }

    // epilogue: C/D layout col = lane&15, row = quad*4 + reg.
    // Block-uniform routing: bn multiples of 128 -> tile entirely alpha or v.
    const bool is_alpha = (bn < D_DIM);
    float* __restrict__ dst = is_alpha ? alpha_dst : v_dst;
    const float* __restrict__ bias = is_alpha ? ba : bv;
    const int nb = bn - (is_alpha ? 0 : D_DIM);
#pragma unroll
    for (int j = 0; j < 4; ++j) {
        const int n = nb + wn * 64 + j * 16 + l16;
        const float bias_n = bias[n];
#pragma unroll
        for (int i = 0; i < 4; ++i) {
            const int m0 = bm + wm * 64 + i * 16 + quad * 4;
#pragma unroll
            for (int r = 0; r < 4; ++r) {
                float val = acc[i][j][r] + bias_n;
                if (is_alpha) val = sigmoidf(val);
                dst[(size_t)(m0 + r) * D_DIM + n] = val;
            }
        }
    }
}

// ---------------- chunked parallel scan ----------------
// h_t = a_t*h_{t-1} + (1-a_t)*v_t  == affine h_out = P*h_in + Q per chunk.

// Phase 1: per (chunk, channel4) compute chunk composition (P,Q).
__global__ __launch_bounds__(256) void scan_phase1_kernel(
    const float4* __restrict__ alpha,  // [T][NCH4]
    const float4* __restrict__ v,      // [T][NCH4]
    float4* __restrict__ P,            // [CHUNKS][NCH4]
    float4* __restrict__ Q) {
    const int j4 = blockIdx.x * 256 + threadIdx.x;  // 0..NCH4-1
    const int c = blockIdx.y;
    float4 Pr = {1.f, 1.f, 1.f, 1.f};
    float4 Qr = {0.f, 0.f, 0.f, 0.f};
    size_t base = (size_t)c * CHUNK_LEN * NCH4 + j4;
#pragma unroll 4
    for (int t = 0; t < CHUNK_LEN; ++t) {
        float4 a = alpha[base + (size_t)t * NCH4];
        float4 vv = v[base + (size_t)t * NCH4];
        Pr.x *= a.x; Pr.y *= a.y; Pr.z *= a.z; Pr.w *= a.w;
        Qr.x = a.x * Qr.x + (1.f - a.x) * vv.x;
        Qr.y = a.y * Qr.y + (1.f - a.y) * vv.y;
        Qr.z = a.z * Qr.z + (1.f - a.z) * vv.z;
        Qr.w = a.w * Qr.w + (1.f - a.w) * vv.w;
    }
    P[(size_t)c * NCH4 + j4] = Pr;
    Q[(size_t)c * NCH4 + j4] = Qr;
}

// Phase 2: exclusive prefix over chunks (2048 threads, 64 sequential steps).
__global__ __launch_bounds__(256) void scan_phase2_kernel(
    const float4* __restrict__ P, const float4* __restrict__ Q,
    const float4* __restrict__ h0,  // [NCH4]
    float4* __restrict__ Hc) {      // [CHUNKS][NCH4] = h at chunk start
    const int j4 = blockIdx.x * 256 + threadIdx.x;
    float4 h = h0[j4];
#pragma unroll 8
    for (int c = 0; c < CHUNKS; ++c) {
        Hc[(size_t)c * NCH4 + j4] = h;
        float4 p = P[(size_t)c * NCH4 + j4];
        float4 q = Q[(size_t)c * NCH4 + j4];
        h.x = p.x * h.x + q.x;
        h.y = p.y * h.y + q.y;
        h.z = p.z * h.z + q.z;
        h.w = p.w * h.w + q.w;
    }
}

// Phase 3: replay chunk with correct incoming h; in-place overwrite:
// alpha region -> output, v region -> h[t+1].
__global__ __launch_bounds__(256) void scan_phase3_kernel(
    float4* __restrict__ alpha_out,  // in: alpha[t], out: output[t]
    float4* __restrict__ v_h,        // in: v[t] (at h[t+1] slot), out: h[t+1]
    const float4* __restrict__ Hc) {
    const int j4 = blockIdx.x * 256 + threadIdx.x;
    const int c = blockIdx.y;
    float4 h = Hc[(size_t)c * NCH4 + j4];
    size_t base = (size_t)c * CHUNK_LEN * NCH4 + j4;
#pragma unroll 4
    for (int t = 0; t < CHUNK_LEN; ++t) {
        float4 a = alpha_out[base + (size_t)t * NCH4];
        float4 vv = v_h[base + (size_t)t * NCH4];
        h.x = a.x * h.x + (1.f - a.x) * vv.x;
        h.y = a.y * h.y + (1.f - a.y) * vv.y;
        h.z = a.z * h.z + (1.f - a.z) * vv.z;
        h.w = a.w * h.w + (1.f - a.w) * vv.w;
        float4 o;
        o.x = h.x * h.x * sigmoidf(h.x);
        o.y = h.y * h.y * sigmoidf(h.y);
        o.z = h.z * h.z * sigmoidf(h.z);
        o.w = h.w * h.w * sigmoidf(h.w);
        alpha_out[base + (size_t)t * NCH4] = o;
        v_h[base + (size_t)t * NCH4] = h;
    }
}

extern "C" void kernel_launch(void* const* d_in, const int* in_sizes, int n_in,
                              void* d_out, int out_size, void* d_ws, size_t ws_size,
                              hipStream_t stream) {
    const float* x  = (const float*)d_in[0];   // [T,B,D]
    const float* h0 = (const float*)d_in[1];   // [B,D]
    const float* Wa = (const float*)d_in[2];   // [D,D]
    const float* ba = (const float*)d_in[3];   // [D]
    const float* Wv = (const float*)d_in[4];   // [D,D]
    const float* bv = (const float*)d_in[5];   // [D]

    float* out = (float*)d_out;                       // output region [T][NCH]
    float* hbase = out + (size_t)T_DIM * NCH;         // h region [T+1][NCH]
    float* alpha = out;                               // temp alpha in output region
    float* vbuf = hbase + NCH;                        // temp v in h[1..T]

    char* ws = (char*)d_ws;
    unsigned short* xb   = (unsigned short*)ws;                      // 32 MB
    unsigned short* Wcat = (unsigned short*)(ws + 33554432);         // 4 MB
    float* P  = (float*)(ws + 37748736);                             // 2 MB
    float* Q  = (float*)(ws + 39845888);                             // 2 MB
    float* Hc = (float*)(ws + 41943040);                             // 2 MB

    // 1. convert inputs to bf16
    f32_to_bf16_kernel<<<(M_DIM * K_DIM / 4) / 256, 256, 0, stream>>>(
        (const float4*)x, (ushort4*)xb, M_DIM * K_DIM / 4);
    conv_weights_kernel<<<(2 * D_DIM * D_DIM / 4) / 256, 256, 0, stream>>>(
        (const float4*)Wa, (const float4*)Wv, (ushort4*)Wcat);

    // 2. fused GEMM: alpha = sigmoid(x Wa^T + ba) -> output region
    //                v     =         x Wv^T + bv  -> h[1..T] region
    dim3 ggrid(NW_DIM / 128, M_DIM / 128);  // (16, 128) = 2048 blocks
    gemm_fused_kernel<<<ggrid, 256, 0, stream>>>(xb, Wcat, ba, bv, alpha, vbuf);

    // 3. h[0] = h0
    hipMemcpyAsync(hbase, h0, (size_t)NCH * sizeof(float),
                   hipMemcpyDeviceToDevice, stream);

    // 4. chunked scan
    dim3 sgrid(NCH4 / 256, CHUNKS);
    scan_phase1_kernel<<<sgrid, 256, 0, stream>>>(
        (const float4*)alpha, (const float4*)vbuf, (float4*)P, (float4*)Q);
    scan_phase2_kernel<<<NCH4 / 256, 256, 0, stream>>>(
        (const float4*)P, (const float4*)Q, (const float4*)h0, (float4*)Hc);
    scan_phase3_kernel<<<sgrid, 256, 0, stream>>>(
        (float4*)alpha, (float4*)vbuf, (const float4*)Hc);
}

// Round 3
// 345.139 us; speedup vs baseline: 1.0877x; 1.0424x over previous
//
#include <hip/hip_runtime.h>
#include <hip/hip_bf16.h>

// Problem constants
#define T_DIM 2048
#define B_DIM 8
#define D_DIM 1024
#define M_DIM (T_DIM * B_DIM)     // 16384
#define K_DIM D_DIM               // 1024
#define NW_DIM (2 * D_DIM)        // 2048 combined GEMM cols (alpha | v)
#define NCH (B_DIM * D_DIM)       // 8192 channels
#define NCH4 (NCH / 4)            // 2048 float4 channels
#define CHUNKS 64
#define CHUNK_LEN 32              // 64*32 = 2048 = T

typedef __attribute__((ext_vector_type(8))) short bf16x8;
typedef __attribute__((ext_vector_type(4))) float f32x4;

__device__ __forceinline__ unsigned short bf16_rne(float f) {
    unsigned u = __float_as_uint(f);
    unsigned r = u + 0x7fffu + ((u >> 16) & 1u);
    return (unsigned short)(r >> 16);
}

__device__ __forceinline__ float sigmoidf(float z) {
    return 1.0f / (1.0f + __expf(-z));
}

__device__ __forceinline__ void load_lds16(const void* g, void* l) {
    __builtin_amdgcn_global_load_lds(
        (const __attribute__((address_space(1))) void*)g,
        (__attribute__((address_space(3))) void*)l,
        16, 0, 0);
}

// ---------------- fp32 -> bf16 convert (x) ----------------
__global__ void f32_to_bf16_kernel(const float4* __restrict__ in,
                                   ushort4* __restrict__ out, int n4) {
    int i = blockIdx.x * blockDim.x + threadIdx.x;
    if (i < n4) {
        float4 f = in[i];
        ushort4 o;
        o.x = bf16_rne(f.x);
        o.y = bf16_rne(f.y);
        o.z = bf16_rne(f.z);
        o.w = bf16_rne(f.w);
        out[i] = o;
    }
}

// ---------------- weights convert: Wcat = [Wa ; Wv] bf16 ----------------
__global__ void conv_weights_kernel(const float4* __restrict__ Wa,
                                    const float4* __restrict__ Wv,
                                    ushort4* __restrict__ Wcat) {
    const int half4 = D_DIM * D_DIM / 4;  // 262144
    int i = blockIdx.x * blockDim.x + threadIdx.x;  // 0 .. 2*half4-1
    float4 f = (i < half4) ? Wa[i] : Wv[i - half4];
    ushort4 o;
    o.x = bf16_rne(f.x);
    o.y = bf16_rne(f.y);
    o.z = bf16_rne(f.z);
    o.w = bf16_rne(f.w);
    Wcat[i] = o;
}

// ---------------- fused bf16 MFMA GEMM ----------------
// A: [M,K] bf16 row-major.  Wcat: [2048,1024] bf16 row-major (B^T layout).
// cols [0,1024): alpha = sigmoid(xWa^T + ba) -> alpha_dst
// cols [1024,2048): v = xWv^T + bv -> v_dst. Both dsts row stride 1024.
// 128x128 block tile, BK=64, 256 threads = 4 waves in 2x2, each wave 64x64
// via 4x4 grid of 16x16x32 MFMAs.
//
// LDS layout is XOR-swizzled to kill bank conflicts: each 128-B row has 8
// 16-B blocks; physical block p of row R stores logical block (p ^ (R&7)).
// Staging respects the global_load_lds "base + lane*16" constraint by
// permuting the *global source column* per lane instead of the LDS dest.
__global__ __launch_bounds__(256) void gemm_fused_kernel(
    const unsigned short* __restrict__ A,
    const unsigned short* __restrict__ W,
    const float* __restrict__ ba,
    const float* __restrict__ bv,
    float* __restrict__ alpha_dst,
    float* __restrict__ v_dst) {
    __shared__ __attribute__((aligned(16))) unsigned short As[128 * 64];
    __shared__ __attribute__((aligned(16))) unsigned short Bs[128 * 64];

    const int tid = threadIdx.x;
    const int lane = tid & 63;
    const int w = tid >> 6;          // wave 0..3
    const int wm = w >> 1;           // wave row (0..1)
    const int wn = w & 1;            // wave col (0..1)
    const int quad = lane >> 4;      // 0..3
    const int l16 = lane & 15;
    const int xr = l16 & 7;          // row swizzle key for fragment reads

    const int bm = blockIdx.y * 128;
    const int bn = blockIdx.x * 128;  // 0..1920, col in the 2048-wide space

    // staging: lane's LDS dest is fixed (base + lane*16); choose its global
    // source so physical block (lane&7) of row st_row holds logical block
    // (lane&7) ^ st_row.
    const int st_row = lane >> 3;                      // 0..7
    const int st_col = ((lane & 7) ^ st_row) * 8;      // swizzled source col

    f32x4 zero = {0.f, 0.f, 0.f, 0.f};
    f32x4 acc[4][4];
#pragma unroll
    for (int i = 0; i < 4; ++i)
#pragma unroll
        for (int j = 0; j < 4; ++j) acc[i][j] = zero;

    for (int kt = 0; kt < K_DIM / 64; ++kt) {
        const int k0 = kt * 64;
#pragma unroll
        for (int j = 0; j < 4; ++j) {
            const int r = w * 32 + j * 8;  // wave-uniform base row
            load_lds16(A + (size_t)(bm + r + st_row) * K_DIM + k0 + st_col,
                       &As[r * 64]);
            load_lds16(W + (size_t)(bn + r + st_row) * K_DIM + k0 + st_col,
                       &Bs[r * 64]);
        }
        __syncthreads();
#pragma unroll
        for (int s = 0; s < 2; ++s) {
            bf16x8 af[4], bfr[4];
#pragma unroll
            for (int i = 0; i < 4; ++i)
                af[i] = *(const bf16x8*)&As[(wm * 64 + i * 16 + l16) * 64 +
                                            (((s * 4 + quad) ^ xr) * 8)];
#pragma unroll
            for (int i = 0; i < 4; ++i)
                bfr[i] = *(const bf16x8*)&Bs[(wn * 64 + i * 16 + l16) * 64 +
                                             (((s * 4 + quad) ^ xr) * 8)];
#pragma unroll
            for (int i = 0; i < 4; ++i)
#pragma unroll
                for (int j = 0; j < 4; ++j)
                    acc[i][j] = __builtin_amdgcn_mfma_f32_16x16x32_bf16(
                        af[i], bfr[j], acc[i][j], 0, 0, 0);
        }
        __syncthreads();
    }

    // epilogue: C/D layout col = lane&15, row = quad*4 + reg.
    // Block-uniform routing: bn multiples of 128 -> tile entirely alpha or v.
    const bool is_alpha = (bn < D_DIM);
    float* __restrict__ dst = is_alpha ? alpha_dst : v_dst;
    const float* __restrict__ bias = is_alpha ? ba : bv;
    const int nb = bn - (is_alpha ? 0 : D_DIM);
#pragma unroll
    for (int j = 0; j < 4; ++j) {
        const int n = nb + wn * 64 + j * 16 + l16;
        const float bias_n = bias[n];
#pragma unroll
        for (int i = 0; i < 4; ++i) {
            const int m0 = bm + wm * 64 + i * 16 + quad * 4;
#pragma unroll
            for (int r = 0; r < 4; ++r) {
                float val = acc[i][j][r] + bias_n;
                if (is_alpha) val = sigmoidf(val);
                dst[(size_t)(m0 + r) * D_DIM + n] = val;
            }
        }
    }
}

// ---------------- chunked parallel scan ----------------
// h_t = a_t*h_{t-1} + (1-a_t)*v_t  == affine h_out = P*h_in + Q per chunk.

// Phase 1: per (chunk, channel4) compute chunk composition (P,Q).
__global__ __launch_bounds__(256) void scan_phase1_kernel(
    const float4* __restrict__ alpha,  // [T][NCH4]
    const float4* __restrict__ v,      // [T][NCH4]
    float4* __restrict__ P,            // [CHUNKS][NCH4]
    float4* __restrict__ Q) {
    const int j4 = blockIdx.x * 256 + threadIdx.x;  // 0..NCH4-1
    const int c = blockIdx.y;
    float4 Pr = {1.f, 1.f, 1.f, 1.f};
    float4 Qr = {0.f, 0.f, 0.f, 0.f};
    size_t base = (size_t)c * CHUNK_LEN * NCH4 + j4;
#pragma unroll 4
    for (int t = 0; t < CHUNK_LEN; ++t) {
        float4 a = alpha[base + (size_t)t * NCH4];
        float4 vv = v[base + (size_t)t * NCH4];
        Pr.x *= a.x; Pr.y *= a.y; Pr.z *= a.z; Pr.w *= a.w;
        Qr.x = a.x * Qr.x + (1.f - a.x) * vv.x;
        Qr.y = a.y * Qr.y + (1.f - a.y) * vv.y;
        Qr.z = a.z * Qr.z + (1.f - a.z) * vv.z;
        Qr.w = a.w * Qr.w + (1.f - a.w) * vv.w;
    }
    P[(size_t)c * NCH4 + j4] = Pr;
    Q[(size_t)c * NCH4 + j4] = Qr;
}

// Phase 2: exclusive prefix over chunks (2048 threads, 64 sequential steps).
__global__ __launch_bounds__(256) void scan_phase2_kernel(
    const float4* __restrict__ P, const float4* __restrict__ Q,
    const float4* __restrict__ h0,  // [NCH4]
    float4* __restrict__ Hc) {      // [CHUNKS][NCH4] = h at chunk start
    const int j4 = blockIdx.x * 256 + threadIdx.x;
    float4 h = h0[j4];
#pragma unroll 8
    for (int c = 0; c < CHUNKS; ++c) {
        Hc[(size_t)c * NCH4 + j4] = h;
        float4 p = P[(size_t)c * NCH4 + j4];
        float4 q = Q[(size_t)c * NCH4 + j4];
        h.x = p.x * h.x + q.x;
        h.y = p.y * h.y + q.y;
        h.z = p.z * h.z + q.z;
        h.w = p.w * h.w + q.w;
    }
}

// Phase 3: replay chunk with correct incoming h; in-place overwrite:
// alpha region -> output, v region -> h[t+1].
__global__ __launch_bounds__(256) void scan_phase3_kernel(
    float4* __restrict__ alpha_out,  // in: alpha[t], out: output[t]
    float4* __restrict__ v_h,        // in: v[t] (at h[t+1] slot), out: h[t+1]
    const float4* __restrict__ Hc) {
    const int j4 = blockIdx.x * 256 + threadIdx.x;
    const int c = blockIdx.y;
    float4 h = Hc[(size_t)c * NCH4 + j4];
    size_t base = (size_t)c * CHUNK_LEN * NCH4 + j4;
#pragma unroll 4
    for (int t = 0; t < CHUNK_LEN; ++t) {
        float4 a = alpha_out[base + (size_t)t * NCH4];
        float4 vv = v_h[base + (size_t)t * NCH4];
        h.x = a.x * h.x + (1.f - a.x) * vv.x;
        h.y = a.y * h.y + (1.f - a.y) * vv.y;
        h.z = a.z * h.z + (1.f - a.z) * vv.z;
        h.w = a.w * h.w + (1.f - a.w) * vv.w;
        float4 o;
        o.x = h.x * h.x * sigmoidf(h.x);
        o.y = h.y * h.y * sigmoidf(h.y);
        o.z = h.z * h.z * sigmoidf(h.z);
        o.w = h.w * h.w * sigmoidf(h.w);
        alpha_out[base + (size_t)t * NCH4] = o;
        v_h[base + (size_t)t * NCH4] = h;
    }
}

extern "C" void kernel_launch(void* const* d_in, const int* in_sizes, int n_in,
                              void* d_out, int out_size, void* d_ws, size_t ws_size,
                              hipStream_t stream) {
    const float* x  = (const float*)d_in[0];   // [T,B,D]
    const float* h0 = (const float*)d_in[1];   // [B,D]
    const float* Wa = (const float*)d_in[2];   // [D,D]
    const float* ba = (const float*)d_in[3];   // [D]
    const float* Wv = (const float*)d_in[4];   // [D,D]
    const float* bv = (const float*)d_in[5];   // [D]

    float* out = (float*)d_out;                       // output region [T][NCH]
    float* hbase = out + (size_t)T_DIM * NCH;         // h region [T+1][NCH]
    float* alpha = out;                               // temp alpha in output region
    float* vbuf = hbase + NCH;                        // temp v in h[1..T]

    char* ws = (char*)d_ws;
    unsigned short* xb   = (unsigned short*)ws;                      // 32 MB
    unsigned short* Wcat = (unsigned short*)(ws + 33554432);         // 4 MB
    float* P  = (float*)(ws + 37748736);                             // 2 MB
    float* Q  = (float*)(ws + 39845888);                             // 2 MB
    float* Hc = (float*)(ws + 41943040);                             // 2 MB

    // 1. convert inputs to bf16
    f32_to_bf16_kernel<<<(M_DIM * K_DIM / 4) / 256, 256, 0, stream>>>(
        (const float4*)x, (ushort4*)xb, M_DIM * K_DIM / 4);
    conv_weights_kernel<<<(2 * D_DIM * D_DIM / 4) / 256, 256, 0, stream>>>(
        (const float4*)Wa, (const float4*)Wv, (ushort4*)Wcat);

    // 2. fused GEMM: alpha = sigmoid(x Wa^T + ba) -> output region
    //                v     =         x Wv^T + bv  -> h[1..T] region
    dim3 ggrid(NW_DIM / 128, M_DIM / 128);  // (16, 128) = 2048 blocks
    gemm_fused_kernel<<<ggrid, 256, 0, stream>>>(xb, Wcat, ba, bv, alpha, vbuf);

    // 3. h[0] = h0
    hipMemcpyAsync(hbase, h0, (size_t)NCH * sizeof(float),
                   hipMemcpyDeviceToDevice, stream);

    // 4. chunked scan
    dim3 sgrid(NCH4 / 256, CHUNKS);
    scan_phase1_kernel<<<sgrid, 256, 0, stream>>>(
        (const float4*)alpha, (const float4*)vbuf, (float4*)P, (float4*)Q);
    scan_phase2_kernel<<<NCH4 / 256, 256, 0, stream>>>(
        (const float4*)P, (const float4*)Q, (const float4*)h0, (float4*)Hc);
    scan_phase3_kernel<<<sgrid, 256, 0, stream>>>(
        (float4*)alpha, (float4*)vbuf, (const float4*)Hc);
}